// Round 12
// baseline (549.624 us; speedup 1.0000x reference)
//
#include <hip/hip_runtime.h>
#include <stdint.h>

#define D_MODEL 2048
#define S_LEN 2048
#define BATCH 4
#define NHEADS 16
#define DK 128
#define M_TOK (BATCH * S_LEN)  // 8192

typedef __attribute__((ext_vector_type(8))) short bf16x8;
typedef __attribute__((ext_vector_type(4))) float f32x4;

__device__ __forceinline__ short f2bf(float f) {  // RNE (GEMM/cvt paths)
  unsigned u = __float_as_uint(f);
  u = (u + 0x7FFF + ((u >> 16) & 1)) >> 16;
  return (short)u;
}
__device__ __forceinline__ short f2bf_fast(float f) {  // round-half-up, 2 ops
  return (short)((__float_as_uint(f) + 0x8000u) >> 16);
}

__device__ __forceinline__ void gl2lds16(const void* g, void* l) {
  __builtin_amdgcn_global_load_lds(
      (const __attribute__((address_space(1))) unsigned int*)g,
      (__attribute__((address_space(3))) unsigned int*)l, 16, 0, 0);
}

#define ASM_BAR() asm volatile("s_barrier" ::: "memory")
#define VMCNT0() asm volatile("s_waitcnt vmcnt(0)" ::: "memory")

// ---------------- fp32 -> bf16 converts, z-batched ---------------------------
__global__ __launch_bounds__(256) void cvt3_kernel(const float* __restrict__ a0,
                                                   const float* __restrict__ a1,
                                                   const float* __restrict__ a2,
                                                   short* o0, short* o1,
                                                   short* o2, int n8) {
  const float* in = (blockIdx.y == 0) ? a0 : (blockIdx.y == 1) ? a1 : a2;
  short* out = (blockIdx.y == 0) ? o0 : (blockIdx.y == 1) ? o1 : o2;
  int i = blockIdx.x * blockDim.x + threadIdx.x;
  const int stride = gridDim.x * blockDim.x;
  for (; i < n8; i += stride) {
    const float4* p = (const float4*)(in + (size_t)i * 8);
    float4 a = p[0], b = p[1];
    bf16x8 o;
    o[0] = f2bf(a.x); o[1] = f2bf(a.y); o[2] = f2bf(a.z); o[3] = f2bf(a.w);
    o[4] = f2bf(b.x); o[5] = f2bf(b.y); o[6] = f2bf(b.z); o[7] = f2bf(b.w);
    *(bf16x8*)(out + (size_t)i * 8) = o;
  }
}

__global__ __launch_bounds__(256) void cvt4_kernel(const float* __restrict__ a0,
                                                   const float* __restrict__ a1,
                                                   const float* __restrict__ a2,
                                                   const float* __restrict__ a3,
                                                   short* o0, short* o1,
                                                   short* o2, short* o3,
                                                   int n8) {
  const float* in = (blockIdx.y == 0)   ? a0
                    : (blockIdx.y == 1) ? a1
                    : (blockIdx.y == 2) ? a2
                                        : a3;
  short* out = (blockIdx.y == 0)   ? o0
               : (blockIdx.y == 1) ? o1
               : (blockIdx.y == 2) ? o2
                                   : o3;
  int i = blockIdx.x * blockDim.x + threadIdx.x;
  const int stride = gridDim.x * blockDim.x;
  for (; i < n8; i += stride) {
    const float4* p = (const float4*)(in + (size_t)i * 8);
    float4 a = p[0], b = p[1];
    bf16x8 o;
    o[0] = f2bf(a.x); o[1] = f2bf(a.y); o[2] = f2bf(a.z); o[3] = f2bf(a.w);
    o[4] = f2bf(b.x); o[5] = f2bf(b.y); o[6] = f2bf(b.z); o[7] = f2bf(b.w);
    *(bf16x8*)(out + (size_t)i * 8) = o;
  }
}

// ---------------- 256x256 GEMM: C[M,N] = A[M,K]*B[N,K]^T + bias --------------
// r7 schedule (best measured): ONE vmcnt(0) + ONE s_barrier per K-tile; next
// tile's 8 staging sweeps issued as a cluster right after the barrier.
// EPI 0/1: MFMA operands SWAPPED (C-frag transposed) so each lane holds 4
// consecutive output COLUMNS -> packed ushort4/float4 stores, float4 bias.
// EPI 0: bf16 head-split [B,H,S,DK], scaled by escale.
// EPI 1: f32 flat [M,N].  EPI 2: bf16 per-head transposed [B,H,DK,S]
// (EPI 2 keeps original operand order: wants 4 consecutive S per lane).
template <int EPI>
__global__ __launch_bounds__(512, 2) void gemm256(const short* __restrict__ A,
                                                  const short* __restrict__ B,
                                                  const float* __restrict__ bias,
                                                  void* __restrict__ Cout,
                                                  float escale) {
  __shared__ short As[2][256 * 64];
  __shared__ short Bs[2][256 * 64];
  const int t = threadIdx.x, lane = t & 63, w = t >> 6;
  const int c = lane & 15, g = lane >> 4;
  const int wr = w >> 2, wc = w & 3;

  const int cpx = (int)gridDim.x >> 3;
  const int swz = ((int)blockIdx.x & 7) * cpx + ((int)blockIdx.x >> 3);
  const int by = swz >> 3, bx = swz & 7;
  const int row0 = by * 256, col0 = bx * 256;
  const int K = D_MODEL;
  const int NT = K / 64;

  const int srow = t >> 3;
  const int sseg = t & 7;
  const int skk = 8 * (sseg ^ (srow & 7));

  const short* Abase = A + (size_t)(row0 + srow) * K;
  const short* Bbase = B + (size_t)(col0 + srow) * K;

#define SWEEPA(p, R, kt)                                              \
  gl2lds16(Abase + (size_t)(R) * 64 * K + (kt) * 64 + skk,            \
           &As[p][(R) * 4096 + t * 8])
#define SWEEPB(p, R, kt)                                              \
  gl2lds16(Bbase + (size_t)(R) * 64 * K + (kt) * 64 + skk,            \
           &Bs[p][(R) * 4096 + t * 8])
#define STAGE_TILE(q, kt1)                                            \
  {                                                                   \
    SWEEPA(q, 0, kt1); SWEEPA(q, 1, kt1);                             \
    SWEEPA(q, 2, kt1); SWEEPA(q, 3, kt1);                             \
    SWEEPB(q, 0, kt1); SWEEPB(q, 1, kt1);                             \
    SWEEPB(q, 2, kt1); SWEEPB(q, 3, kt1);                             \
  }

  f32x4 acc[8][4] = {};

  // prologue: stage K-tile 0 into buf0
  STAGE_TILE(0, 0);

  for (int kt = 0; kt < NT; ++kt) {
    const int p = kt & 1, q = p ^ 1;
    VMCNT0();   // drain buf-p loads (issued one full K-tile ago)
    ASM_BAR();  // all waves: done reading old buf q, buf p visible
    if (kt + 1 < NT) STAGE_TILE(q, kt + 1);

    const char* abase = (const char*)As[p];
    const char* bbase = (const char*)Bs[p];
#pragma unroll
    for (int ks = 0; ks < 2; ++ks) {
      const int kb = (ks * 64 + g * 16) ^ ((c & 7) << 4);
      bf16x8 bfr[4];
#pragma unroll
      for (int ni = 0; ni < 4; ++ni)
        bfr[ni] = *(const bf16x8*)(bbase + (wc * 64 + ni * 16 + c) * 128 + kb);
#pragma unroll
      for (int mg = 0; mg < 2; ++mg) {
        bf16x8 afr[4];
#pragma unroll
        for (int mi = 0; mi < 4; ++mi)
          afr[mi] = *(const bf16x8*)(abase +
                                     (wr * 128 + mg * 64 + mi * 16 + c) * 128 +
                                     kb);
        __builtin_amdgcn_s_setprio(1);
#pragma unroll
        for (int mi = 0; mi < 4; ++mi)
#pragma unroll
          for (int ni = 0; ni < 4; ++ni) {
            if (EPI == 2)
              acc[mg * 4 + mi][ni] = __builtin_amdgcn_mfma_f32_16x16x32_bf16(
                  afr[mi], bfr[ni], acc[mg * 4 + mi][ni], 0, 0, 0);
            else  // swapped: lane holds 4 consecutive cols (transposed C-frag)
              acc[mg * 4 + mi][ni] = __builtin_amdgcn_mfma_f32_16x16x32_bf16(
                  bfr[ni], afr[mi], acc[mg * 4 + mi][ni], 0, 0, 0);
          }
        __builtin_amdgcn_s_setprio(0);
      }
    }
  }

  if (EPI == 2) {
    // original orientation: lane holds 4 consecutive M-rows (s) at fixed col
#pragma unroll
    for (int ni = 0; ni < 4; ++ni) {
      const int col = col0 + wc * 64 + ni * 16 + c;
      const float bv = bias[col];
#pragma unroll
      for (int m = 0; m < 8; ++m) {
        const int rbase =
            row0 + wr * 128 + (m >> 2) * 64 + (m & 3) * 16 + g * 4;
        const int h = col >> 7, dk = col & 127;
        const int b = rbase >> 11, s0 = rbase & 2047;
        ushort4 pk;
        pk.x = (unsigned short)f2bf(acc[m][ni][0] + bv);
        pk.y = (unsigned short)f2bf(acc[m][ni][1] + bv);
        pk.z = (unsigned short)f2bf(acc[m][ni][2] + bv);
        pk.w = (unsigned short)f2bf(acc[m][ni][3] + bv);
        *(ushort4*)&((short*)Cout)[(((size_t)b * NHEADS + h) * DK + dk) *
                                       S_LEN + s0] = pk;
      }
    }
  } else {
    // swapped orientation: lane holds cols col..col+3 at fixed row s
#pragma unroll
    for (int ni = 0; ni < 4; ++ni) {
      const int col = col0 + wc * 64 + ni * 16 + g * 4;
      const float4 bv4 = *(const float4*)&bias[col];
#pragma unroll
      for (int m = 0; m < 8; ++m) {
        const int s = row0 + wr * 128 + (m >> 2) * 64 + (m & 3) * 16 + c;
        if (EPI == 0) {
          const int h = col >> 7, dk = col & 127;
          const int b = s >> 11, ss = s & 2047;
          ushort4 pk;
          pk.x = (unsigned short)f2bf((acc[m][ni][0] + bv4.x) * escale);
          pk.y = (unsigned short)f2bf((acc[m][ni][1] + bv4.y) * escale);
          pk.z = (unsigned short)f2bf((acc[m][ni][2] + bv4.z) * escale);
          pk.w = (unsigned short)f2bf((acc[m][ni][3] + bv4.w) * escale);
          *(ushort4*)&((short*)Cout)[(((size_t)b * NHEADS + h) * S_LEN + ss) *
                                         DK + dk] = pk;
        } else {
          float4 v;
          v.x = acc[m][ni][0] + bv4.x;
          v.y = acc[m][ni][1] + bv4.y;
          v.z = acc[m][ni][2] + bv4.z;
          v.w = acc[m][ni][3] + bv4.w;
          *(float4*)&((float*)Cout)[(size_t)s * D_MODEL + col] = v;
        }
      }
    }
  }
#undef SWEEPA
#undef SWEEPB
#undef STAGE_TILE
}

// ---------------- causal flash attention (4 waves, QBLK=128, dbuf, 80KB LDS) -
// Q is PRE-SCALED by log2(e)/sqrt(128) in the Q-GEMM epilogue.
// Block map: XCD x gets heads 8x..8x+7; co-resident window spans ~4 heads
// (4 MB K/V -> L2-resident), qt descending within each head (big-first).
__global__ __launch_bounds__(256, 2) void attn_kernel(
    const short* __restrict__ Qp, const short* __restrict__ Kp,
    const short* __restrict__ Vt, short* __restrict__ ctx) {
  const int t = threadIdx.x, lane = t & 63, w = t >> 6;  // w in 0..3
  const int c = lane & 15, g = lane >> 4;

  const int fid = blockIdx.x;
  const int x = fid & 7, u = fid >> 3;  // u in 0..127
  const int bh = (x << 3) | (u >> 4);   // 8 heads per XCD, ~4 co-resident
  const int qt = 15 - (u & 15);         // big q-blocks first per head
  const int b = bh >> 4, h = bh & 15;

  __shared__ short Kl[2][64 * 128];  // swizzled: seg ^= row&7   (32 KB)
  __shared__ short Vl[2][128 * 64];  // swizzled: seg ^= row&7   (32 KB)
  __shared__ short Pl[4][32][64];    // swizzled: seg ^= row&7   (16 KB)

  const short* Kbase = Kp + (size_t)bh * S_LEN * DK;
  const short* Vbase = Vt + (size_t)bh * DK * S_LEN;

  const int qbase = qt * 128 + w * 32;
  const short* Qg = Qp + ((size_t)bh * S_LEN + qbase + c) * DK;
  bf16x8 aq[2][4];
#pragma unroll
  for (int mi = 0; mi < 2; ++mi)
#pragma unroll
    for (int kc = 0; kc < 4; ++kc)
      aq[mi][kc] = *(const bf16x8*)(Qg + mi * 16 * DK + kc * 32 + g * 8);

  float mprev[2][4], lsum[2][4];  // lsum = PER-LANE partial (reduced at end)
  f32x4 accO[2][8] = {};
#pragma unroll
  for (int mi = 0; mi < 2; ++mi)
#pragma unroll
    for (int r = 0; r < 4; ++r) {
      mprev[mi][r] = -3.0e38f;
      lsum[mi][r] = 0.f;
    }

  const int nt = 2 * qt + 2;
  const int jmax = (qbase + 31) >> 6;

  auto stage = [&](int buf, int j) {
    const short* Kg = Kbase + (size_t)j * 64 * DK;
#pragma unroll
    for (int ii = 0; ii < 4; ++ii) {
      int s = t + 256 * ii;
      int row = s >> 4, cs = s & 15;
      gl2lds16(Kg + row * DK + (cs ^ (row & 7)) * 8, &Kl[buf][s * 8]);
    }
    const short* Vg = Vbase + j * 64;
#pragma unroll
    for (int ii = 0; ii < 4; ++ii) {
      int s = t + 256 * ii;
      int row = s >> 3, cs = s & 7;
      gl2lds16(Vg + (size_t)row * S_LEN + (cs ^ (row & 7)) * 8,
               &Vl[buf][s * 8]);
    }
  };

  stage(0, 0);
  __syncthreads();
  int cur = 0;

  for (int j = 0; j < nt; ++j) {
    if (j + 1 < nt) stage(cur ^ 1, j + 1);

    if (j <= jmax) {
      // ---- QK^T: 32q x 64k per wave (scores pre-scaled) ----
      f32x4 sa[2][4];
#pragma unroll
      for (int mi = 0; mi < 2; ++mi)
#pragma unroll
        for (int nf = 0; nf < 4; ++nf) sa[mi][nf] = (f32x4){0.f, 0.f, 0.f, 0.f};
      __builtin_amdgcn_s_setprio(1);
#pragma unroll
      for (int nf = 0; nf < 4; ++nf) {
#pragma unroll
        for (int kc = 0; kc < 4; ++kc) {
          const int row = nf * 16 + c;
          const int seg = kc * 4 + g;
          bf16x8 bk = *(const bf16x8*)((const char*)&Kl[cur][0] + row * 256 +
                                       ((seg ^ (row & 7)) << 4));
#pragma unroll
          for (int mi = 0; mi < 2; ++mi)
            sa[mi][nf] = __builtin_amdgcn_mfma_f32_16x16x32_bf16(
                aq[mi][kc], bk, sa[mi][nf], 0, 0, 0);
        }
      }
      __builtin_amdgcn_s_setprio(0);

      // ---- causal mask: wave-uniform branch ----
#pragma unroll
      for (int mi = 0; mi < 2; ++mi) {
        if (j * 64 + 63 > qbase + mi * 16) {
#pragma unroll
          for (int r = 0; r < 4; ++r) {
            const int qglob = qbase + mi * 16 + g * 4 + r;
#pragma unroll
            for (int nf = 0; nf < 4; ++nf)
              if ((j * 64 + nf * 16 + c) > qglob) sa[mi][nf][r] = -3.0e38f;
          }
        }
      }

      // ---- per-lane max + vote (no shuffle tree in the common path) ----
      float lmax[2][4];
      bool need = false;
#pragma unroll
      for (int mi = 0; mi < 2; ++mi)
#pragma unroll
        for (int r = 0; r < 4; ++r) {
          const float m0 = fmaxf(fmaxf(sa[mi][0][r], sa[mi][1][r]),
                                 fmaxf(sa[mi][2][r], sa[mi][3][r]));
          lmax[mi][r] = m0;
          need = need || (m0 > mprev[mi][r] + 5.101f);
        }
      if (__any((int)need)) {  // rare: true row max + rescale
#pragma unroll
        for (int mi = 0; mi < 2; ++mi)
#pragma unroll
          for (int r = 0; r < 4; ++r) {
            float m0 = lmax[mi][r];
            m0 = fmaxf(m0, __shfl_xor(m0, 1));
            m0 = fmaxf(m0, __shfl_xor(m0, 2));
            m0 = fmaxf(m0, __shfl_xor(m0, 4));
            m0 = fmaxf(m0, __shfl_xor(m0, 8));
            const float nm = fmaxf(mprev[mi][r], m0);
            const float corr = exp2f(mprev[mi][r] - nm);
            lsum[mi][r] *= corr;
#pragma unroll
            for (int no = 0; no < 8; ++no) accO[mi][no][r] *= corr;
            mprev[mi][r] = nm;
          }
      }

      // ---- exp2 + P store (cheap round) + per-lane lsum partial ----
#pragma unroll
      for (int mi = 0; mi < 2; ++mi)
#pragma unroll
        for (int r = 0; r < 4; ++r) {
          const float nm = mprev[mi][r];
          const int prow = mi * 16 + g * 4 + r;
          float rs = 0.f;
#pragma unroll
          for (int nf = 0; nf < 4; ++nf) {
            const float pp = exp2f(sa[mi][nf][r] - nm);
            rs += pp;
            const int col = nf * 16 + c;
            *(short*)((char*)&Pl[w][0][0] + prow * 128 +
                      (((col >> 3) ^ (prow & 7)) << 4) + (col & 7) * 2) =
                f2bf_fast(pp);
          }
          lsum[mi][r] += rs;
        }

      // ---- PV: ctx32x128 += P32x64 * V64x128 ----
      bf16x8 ap[2][2];
#pragma unroll
      for (int mi = 0; mi < 2; ++mi)
#pragma unroll
        for (int kc = 0; kc < 2; ++kc) {
          const int prow = mi * 16 + c;
          const int kseg = kc * 4 + g;
          ap[mi][kc] = *(const bf16x8*)((const char*)&Pl[w][0][0] +
                                        prow * 128 +
                                        ((kseg ^ (prow & 7)) << 4));
        }
      __builtin_amdgcn_s_setprio(1);
#pragma unroll
      for (int no = 0; no < 8; ++no) {
#pragma unroll
        for (int kc = 0; kc < 2; ++kc) {
          const int row = no * 16 + c;
          const int seg = kc * 4 + g;
          bf16x8 bv = *(const bf16x8*)((const char*)&Vl[cur][0] + row * 128 +
                                       ((seg ^ (row & 7)) << 4));
#pragma unroll
          for (int mi = 0; mi < 2; ++mi)
            accO[mi][no] = __builtin_amdgcn_mfma_f32_16x16x32_bf16(
                ap[mi][kc], bv, accO[mi][no], 0, 0, 0);
        }
      }
      __builtin_amdgcn_s_setprio(0);
    }

    __syncthreads();
    cur ^= 1;
  }

#pragma unroll
  for (int mi = 0; mi < 2; ++mi) {
    const int qrow = qbase + mi * 16 + g * 4;
#pragma unroll
    for (int r = 0; r < 4; ++r) {
      float ls = lsum[mi][r];  // epilogue cross-lane reduce (once per block)
      ls += __shfl_xor(ls, 1);
      ls += __shfl_xor(ls, 2);
      ls += __shfl_xor(ls, 4);
      ls += __shfl_xor(ls, 8);
      const float inv = 1.f / ls;
#pragma unroll
      for (int no = 0; no < 8; ++no) {
        ctx[((size_t)b * S_LEN + qrow + r) * D_MODEL + h * DK + no * 16 + c] =
            f2bf_fast(accO[mi][no][r] * inv);
      }
    }
  }
}

// -----------------------------------------------------------------------------
extern "C" void kernel_launch(void* const* d_in, const int* in_sizes, int n_in,
                              void* d_out, int out_size, void* d_ws,
                              size_t ws_size, hipStream_t stream) {
  const float* query = (const float*)d_in[0];
  const float* key = (const float*)d_in[1];
  const float* value = (const float*)d_in[2];
  // d_in[3] = mask (known causal tril; not needed)
  const float* W_q = (const float*)d_in[4];
  const float* b_q = (const float*)d_in[5];
  const float* W_k = (const float*)d_in[6];
  const float* b_k = (const float*)d_in[7];
  const float* W_v = (const float*)d_in[8];
  const float* b_v = (const float*)d_in[9];
  const float* W_o = (const float*)d_in[10];
  const float* b_o = (const float*)d_in[11];
  float* out = (float*)d_out;

  char* p = (char*)d_ws;
  const size_t WSZ = (size_t)D_MODEL * D_MODEL * 2;       // 8 MiB
  const size_t XSZ = (size_t)M_TOK * D_MODEL * 2;         // 32 MiB
  short* wq = (short*)p; p += WSZ;
  short* wk = (short*)p; p += WSZ;
  short* wv = (short*)p; p += WSZ;
  short* wo = (short*)p; p += WSZ;
  short* xq = (short*)p; p += XSZ;  // query bf16, later reused as ctx
  short* xk = (short*)p; p += XSZ;  // key bf16
  short* xv = (short*)p; p += XSZ;  // value bf16
  short* Qp = (short*)p; p += XSZ;
  short* Kp = (short*)p; p += XSZ;
  short* Vt = (short*)p; p += XSZ;  // V^T per head

  const int nX8 = (M_TOK * D_MODEL) / 8;
  const int nW8 = (D_MODEL * D_MODEL) / 8;
  cvt3_kernel<<<dim3(1024, 3), 256, 0, stream>>>(query, key, value, xq, xk, xv,
                                                 nX8);
  cvt4_kernel<<<dim3(512, 4), 256, 0, stream>>>(W_q, W_k, W_v, W_o, wq, wk, wv,
                                                wo, nW8);

  const float qscale = 0.12753101829629947f;  // log2(e)/sqrt(128)
  const int ngemm = (M_TOK / 256) * (D_MODEL / 256);  // 256 blocks

  gemm256<0><<<ngemm, 512, 0, stream>>>(xq, wq, b_q, Qp, qscale);
  gemm256<0><<<ngemm, 512, 0, stream>>>(xk, wk, b_k, Kp, 1.0f);
  gemm256<2><<<ngemm, 512, 0, stream>>>(xv, wv, b_v, Vt, 1.0f);

  // 1024 blocks: 64 bh x 16 q-tiles of 128 rows, XCD-mapped in-kernel
  attn_kernel<<<dim3(16 * BATCH * NHEADS), 256, 0, stream>>>(Qp, Kp, Vt, xq);

  gemm256<1><<<256, 512, 0, stream>>>(xq, wo, b_o, out, 1.0f);
}

// Round 13
// 496.223 us; speedup vs baseline: 1.1076x; 1.1076x over previous
//
#include <hip/hip_runtime.h>
#include <stdint.h>

#define D_MODEL 2048
#define S_LEN 2048
#define BATCH 4
#define NHEADS 16
#define DK 128
#define M_TOK (BATCH * S_LEN)  // 8192

typedef __attribute__((ext_vector_type(8))) short bf16x8;
typedef __attribute__((ext_vector_type(4))) float f32x4;

__device__ __forceinline__ short f2bf(float f) {  // RNE (GEMM/cvt paths)
  unsigned u = __float_as_uint(f);
  u = (u + 0x7FFF + ((u >> 16) & 1)) >> 16;
  return (short)u;
}
__device__ __forceinline__ short f2bf_fast(float f) {  // round-half-up, 2 ops
  return (short)((__float_as_uint(f) + 0x8000u) >> 16);
}

__device__ __forceinline__ void gl2lds16(const void* g, void* l) {
  __builtin_amdgcn_global_load_lds(
      (const __attribute__((address_space(1))) unsigned int*)g,
      (__attribute__((address_space(3))) unsigned int*)l, 16, 0, 0);
}

#define ASM_BAR() asm volatile("s_barrier" ::: "memory")
#define VMCNT0() asm volatile("s_waitcnt vmcnt(0)" ::: "memory")

// ---------------- fp32 -> bf16 converts, z-batched ---------------------------
__global__ __launch_bounds__(256) void cvt3_kernel(const float* __restrict__ a0,
                                                   const float* __restrict__ a1,
                                                   const float* __restrict__ a2,
                                                   short* o0, short* o1,
                                                   short* o2, int n8) {
  const float* in = (blockIdx.y == 0) ? a0 : (blockIdx.y == 1) ? a1 : a2;
  short* out = (blockIdx.y == 0) ? o0 : (blockIdx.y == 1) ? o1 : o2;
  int i = blockIdx.x * blockDim.x + threadIdx.x;
  const int stride = gridDim.x * blockDim.x;
  for (; i < n8; i += stride) {
    const float4* p = (const float4*)(in + (size_t)i * 8);
    float4 a = p[0], b = p[1];
    bf16x8 o;
    o[0] = f2bf(a.x); o[1] = f2bf(a.y); o[2] = f2bf(a.z); o[3] = f2bf(a.w);
    o[4] = f2bf(b.x); o[5] = f2bf(b.y); o[6] = f2bf(b.z); o[7] = f2bf(b.w);
    *(bf16x8*)(out + (size_t)i * 8) = o;
  }
}

__global__ __launch_bounds__(256) void cvt4_kernel(const float* __restrict__ a0,
                                                   const float* __restrict__ a1,
                                                   const float* __restrict__ a2,
                                                   const float* __restrict__ a3,
                                                   short* o0, short* o1,
                                                   short* o2, short* o3,
                                                   int n8) {
  const float* in = (blockIdx.y == 0)   ? a0
                    : (blockIdx.y == 1) ? a1
                    : (blockIdx.y == 2) ? a2
                                        : a3;
  short* out = (blockIdx.y == 0)   ? o0
               : (blockIdx.y == 1) ? o1
               : (blockIdx.y == 2) ? o2
                                   : o3;
  int i = blockIdx.x * blockDim.x + threadIdx.x;
  const int stride = gridDim.x * blockDim.x;
  for (; i < n8; i += stride) {
    const float4* p = (const float4*)(in + (size_t)i * 8);
    float4 a = p[0], b = p[1];
    bf16x8 o;
    o[0] = f2bf(a.x); o[1] = f2bf(a.y); o[2] = f2bf(a.z); o[3] = f2bf(a.w);
    o[4] = f2bf(b.x); o[5] = f2bf(b.y); o[6] = f2bf(b.z); o[7] = f2bf(b.w);
    *(bf16x8*)(out + (size_t)i * 8) = o;
  }
}

// ---------------- 256x256 GEMM: C[M,N] = A[M,K]*B[N,K]^T + bias --------------
// r7 schedule (best measured): ONE vmcnt(0) + ONE s_barrier per K-tile; next
// tile's 8 staging sweeps issued as a cluster right after the barrier.
// EPI 0/1: MFMA operands SWAPPED (C-frag transposed) so each lane holds 4
// consecutive output COLUMNS -> packed ushort4/float4 stores, float4 bias.
// EPI 0: bf16 head-split [B,H,S,DK], scaled by escale.
// EPI 1: f32 flat [M,N].  EPI 2: bf16 per-head transposed [B,H,DK,S]
// (EPI 2 keeps original operand order: wants 4 consecutive S per lane).
template <int EPI>
__global__ __launch_bounds__(512, 2) void gemm256(const short* __restrict__ A,
                                                  const short* __restrict__ B,
                                                  const float* __restrict__ bias,
                                                  void* __restrict__ Cout,
                                                  float escale) {
  __shared__ short As[2][256 * 64];
  __shared__ short Bs[2][256 * 64];
  const int t = threadIdx.x, lane = t & 63, w = t >> 6;
  const int c = lane & 15, g = lane >> 4;
  const int wr = w >> 2, wc = w & 3;

  const int cpx = (int)gridDim.x >> 3;
  const int swz = ((int)blockIdx.x & 7) * cpx + ((int)blockIdx.x >> 3);
  const int by = swz >> 3, bx = swz & 7;
  const int row0 = by * 256, col0 = bx * 256;
  const int K = D_MODEL;
  const int NT = K / 64;

  const int srow = t >> 3;
  const int sseg = t & 7;
  const int skk = 8 * (sseg ^ (srow & 7));

  const short* Abase = A + (size_t)(row0 + srow) * K;
  const short* Bbase = B + (size_t)(col0 + srow) * K;

#define SWEEPA(p, R, kt)                                              \
  gl2lds16(Abase + (size_t)(R) * 64 * K + (kt) * 64 + skk,            \
           &As[p][(R) * 4096 + t * 8])
#define SWEEPB(p, R, kt)                                              \
  gl2lds16(Bbase + (size_t)(R) * 64 * K + (kt) * 64 + skk,            \
           &Bs[p][(R) * 4096 + t * 8])
#define STAGE_TILE(q, kt1)                                            \
  {                                                                   \
    SWEEPA(q, 0, kt1); SWEEPA(q, 1, kt1);                             \
    SWEEPA(q, 2, kt1); SWEEPA(q, 3, kt1);                             \
    SWEEPB(q, 0, kt1); SWEEPB(q, 1, kt1);                             \
    SWEEPB(q, 2, kt1); SWEEPB(q, 3, kt1);                             \
  }

  f32x4 acc[8][4] = {};

  // prologue: stage K-tile 0 into buf0
  STAGE_TILE(0, 0);

  for (int kt = 0; kt < NT; ++kt) {
    const int p = kt & 1, q = p ^ 1;
    VMCNT0();   // drain buf-p loads (issued one full K-tile ago)
    ASM_BAR();  // all waves: done reading old buf q, buf p visible
    if (kt + 1 < NT) STAGE_TILE(q, kt + 1);

    const char* abase = (const char*)As[p];
    const char* bbase = (const char*)Bs[p];
#pragma unroll
    for (int ks = 0; ks < 2; ++ks) {
      const int kb = (ks * 64 + g * 16) ^ ((c & 7) << 4);
      bf16x8 bfr[4];
#pragma unroll
      for (int ni = 0; ni < 4; ++ni)
        bfr[ni] = *(const bf16x8*)(bbase + (wc * 64 + ni * 16 + c) * 128 + kb);
#pragma unroll
      for (int mg = 0; mg < 2; ++mg) {
        bf16x8 afr[4];
#pragma unroll
        for (int mi = 0; mi < 4; ++mi)
          afr[mi] = *(const bf16x8*)(abase +
                                     (wr * 128 + mg * 64 + mi * 16 + c) * 128 +
                                     kb);
        __builtin_amdgcn_s_setprio(1);
#pragma unroll
        for (int mi = 0; mi < 4; ++mi)
#pragma unroll
          for (int ni = 0; ni < 4; ++ni) {
            if (EPI == 2)
              acc[mg * 4 + mi][ni] = __builtin_amdgcn_mfma_f32_16x16x32_bf16(
                  afr[mi], bfr[ni], acc[mg * 4 + mi][ni], 0, 0, 0);
            else  // swapped: lane holds 4 consecutive cols (transposed C-frag)
              acc[mg * 4 + mi][ni] = __builtin_amdgcn_mfma_f32_16x16x32_bf16(
                  bfr[ni], afr[mi], acc[mg * 4 + mi][ni], 0, 0, 0);
          }
        __builtin_amdgcn_s_setprio(0);
      }
    }
  }

  if (EPI == 2) {
    // original orientation: lane holds 4 consecutive M-rows (s) at fixed col
#pragma unroll
    for (int ni = 0; ni < 4; ++ni) {
      const int col = col0 + wc * 64 + ni * 16 + c;
      const float bv = bias[col];
#pragma unroll
      for (int m = 0; m < 8; ++m) {
        const int rbase =
            row0 + wr * 128 + (m >> 2) * 64 + (m & 3) * 16 + g * 4;
        const int h = col >> 7, dk = col & 127;
        const int b = rbase >> 11, s0 = rbase & 2047;
        ushort4 pk;
        pk.x = (unsigned short)f2bf(acc[m][ni][0] + bv);
        pk.y = (unsigned short)f2bf(acc[m][ni][1] + bv);
        pk.z = (unsigned short)f2bf(acc[m][ni][2] + bv);
        pk.w = (unsigned short)f2bf(acc[m][ni][3] + bv);
        *(ushort4*)&((short*)Cout)[(((size_t)b * NHEADS + h) * DK + dk) *
                                       S_LEN + s0] = pk;
      }
    }
  } else {
    // swapped orientation: lane holds cols col..col+3 at fixed row s
#pragma unroll
    for (int ni = 0; ni < 4; ++ni) {
      const int col = col0 + wc * 64 + ni * 16 + g * 4;
      const float4 bv4 = *(const float4*)&bias[col];
#pragma unroll
      for (int m = 0; m < 8; ++m) {
        const int s = row0 + wr * 128 + (m >> 2) * 64 + (m & 3) * 16 + c;
        if (EPI == 0) {
          const int h = col >> 7, dk = col & 127;
          const int b = s >> 11, ss = s & 2047;
          ushort4 pk;
          pk.x = (unsigned short)f2bf((acc[m][ni][0] + bv4.x) * escale);
          pk.y = (unsigned short)f2bf((acc[m][ni][1] + bv4.y) * escale);
          pk.z = (unsigned short)f2bf((acc[m][ni][2] + bv4.z) * escale);
          pk.w = (unsigned short)f2bf((acc[m][ni][3] + bv4.w) * escale);
          *(ushort4*)&((short*)Cout)[(((size_t)b * NHEADS + h) * S_LEN + ss) *
                                         DK + dk] = pk;
        } else {
          float4 v;
          v.x = acc[m][ni][0] + bv4.x;
          v.y = acc[m][ni][1] + bv4.y;
          v.z = acc[m][ni][2] + bv4.z;
          v.w = acc[m][ni][3] + bv4.w;
          *(float4*)&((float*)Cout)[(size_t)s * D_MODEL + col] = v;
        }
      }
    }
  }
#undef SWEEPA
#undef SWEEPB
#undef STAGE_TILE
}

// ---------------- causal flash attention (4 waves, QBLK=128, dbuf, 80KB LDS) -
// Q is PRE-SCALED by log2(e)/sqrt(128) in the Q-GEMM epilogue.
// Block map (r11, proven): bh=((u&7)<<3)|x, qt=15-(u>>3) -> globally
// longest-first dispatch (LPT), uniform work per co-resident cohort.
__global__ __launch_bounds__(256, 2) void attn_kernel(
    const short* __restrict__ Qp, const short* __restrict__ Kp,
    const short* __restrict__ Vt, short* __restrict__ ctx) {
  const int t = threadIdx.x, lane = t & 63, w = t >> 6;  // w in 0..3
  const int c = lane & 15, g = lane >> 4;

  const int fid = blockIdx.x;
  const int x = fid & 7, u = fid >> 3;  // u in 0..127
  const int bh = ((u & 7) << 3) | x;
  const int qt = 15 - (u >> 3);
  const int b = bh >> 4, h = bh & 15;

  __shared__ short Kl[2][64 * 128];  // swizzled: seg ^= row&7   (32 KB)
  __shared__ short Vl[2][128 * 64];  // swizzled: seg ^= row&7   (32 KB)
  __shared__ short Pl[4][32][64];    // swizzled: seg ^= row&7   (16 KB)

  const short* Kbase = Kp + (size_t)bh * S_LEN * DK;
  const short* Vbase = Vt + (size_t)bh * DK * S_LEN;

  const int qbase = qt * 128 + w * 32;
  const short* Qg = Qp + ((size_t)bh * S_LEN + qbase + c) * DK;
  bf16x8 aq[2][4];
#pragma unroll
  for (int mi = 0; mi < 2; ++mi)
#pragma unroll
    for (int kc = 0; kc < 4; ++kc)
      aq[mi][kc] = *(const bf16x8*)(Qg + mi * 16 * DK + kc * 32 + g * 8);

  float mprev[2][4], lsum[2][4];  // lsum = PER-LANE partial (reduced at end)
  f32x4 accO[2][8] = {};
#pragma unroll
  for (int mi = 0; mi < 2; ++mi)
#pragma unroll
    for (int r = 0; r < 4; ++r) {
      mprev[mi][r] = -3.0e38f;
      lsum[mi][r] = 0.f;
    }

  const int nt = 2 * qt + 2;
  const int jmax = (qbase + 31) >> 6;

  auto stage = [&](int buf, int j) {
    const short* Kg = Kbase + (size_t)j * 64 * DK;
#pragma unroll
    for (int ii = 0; ii < 4; ++ii) {
      int s = t + 256 * ii;
      int row = s >> 4, cs = s & 15;
      gl2lds16(Kg + row * DK + (cs ^ (row & 7)) * 8, &Kl[buf][s * 8]);
    }
    const short* Vg = Vbase + j * 64;
#pragma unroll
    for (int ii = 0; ii < 4; ++ii) {
      int s = t + 256 * ii;
      int row = s >> 3, cs = s & 7;
      gl2lds16(Vg + (size_t)row * S_LEN + (cs ^ (row & 7)) * 8,
               &Vl[buf][s * 8]);
    }
  };

  stage(0, 0);
  __syncthreads();
  int cur = 0;

  for (int j = 0; j < nt; ++j) {
    if (j + 1 < nt) stage(cur ^ 1, j + 1);

    if (j <= jmax) {
      // ---- QK^T: 32q x 64k per wave (scores pre-scaled) ----
      f32x4 sa[2][4];
#pragma unroll
      for (int mi = 0; mi < 2; ++mi)
#pragma unroll
        for (int nf = 0; nf < 4; ++nf) sa[mi][nf] = (f32x4){0.f, 0.f, 0.f, 0.f};
      __builtin_amdgcn_s_setprio(1);
#pragma unroll
      for (int nf = 0; nf < 4; ++nf) {
#pragma unroll
        for (int kc = 0; kc < 4; ++kc) {
          const int row = nf * 16 + c;
          const int seg = kc * 4 + g;
          bf16x8 bk = *(const bf16x8*)((const char*)&Kl[cur][0] + row * 256 +
                                       ((seg ^ (row & 7)) << 4));
#pragma unroll
          for (int mi = 0; mi < 2; ++mi)
            sa[mi][nf] = __builtin_amdgcn_mfma_f32_16x16x32_bf16(
                aq[mi][kc], bk, sa[mi][nf], 0, 0, 0);
        }
      }
      __builtin_amdgcn_s_setprio(0);

      // ---- causal mask: wave-uniform branch ----
#pragma unroll
      for (int mi = 0; mi < 2; ++mi) {
        if (j * 64 + 63 > qbase + mi * 16) {
#pragma unroll
          for (int r = 0; r < 4; ++r) {
            const int qglob = qbase + mi * 16 + g * 4 + r;
#pragma unroll
            for (int nf = 0; nf < 4; ++nf)
              if ((j * 64 + nf * 16 + c) > qglob) sa[mi][nf][r] = -3.0e38f;
          }
        }
      }

      // ---- per-lane max + vote (no shuffle tree in the common path) ----
      float lmax[2][4];
      bool need = false;
#pragma unroll
      for (int mi = 0; mi < 2; ++mi)
#pragma unroll
        for (int r = 0; r < 4; ++r) {
          const float m0 = fmaxf(fmaxf(sa[mi][0][r], sa[mi][1][r]),
                                 fmaxf(sa[mi][2][r], sa[mi][3][r]));
          lmax[mi][r] = m0;
          need = need || (m0 > mprev[mi][r] + 5.101f);
        }
      if (__any((int)need)) {  // rare: true row max + rescale
#pragma unroll
        for (int mi = 0; mi < 2; ++mi)
#pragma unroll
          for (int r = 0; r < 4; ++r) {
            float m0 = lmax[mi][r];
            m0 = fmaxf(m0, __shfl_xor(m0, 1));
            m0 = fmaxf(m0, __shfl_xor(m0, 2));
            m0 = fmaxf(m0, __shfl_xor(m0, 4));
            m0 = fmaxf(m0, __shfl_xor(m0, 8));
            const float nm = fmaxf(mprev[mi][r], m0);
            const float corr = exp2f(mprev[mi][r] - nm);
            lsum[mi][r] *= corr;
#pragma unroll
            for (int no = 0; no < 8; ++no) accO[mi][no][r] *= corr;
            mprev[mi][r] = nm;
          }
      }

      // ---- exp2 + P store (cheap round) + per-lane lsum partial ----
#pragma unroll
      for (int mi = 0; mi < 2; ++mi)
#pragma unroll
        for (int r = 0; r < 4; ++r) {
          const float nm = mprev[mi][r];
          const int prow = mi * 16 + g * 4 + r;
          float rs = 0.f;
#pragma unroll
          for (int nf = 0; nf < 4; ++nf) {
            const float pp = exp2f(sa[mi][nf][r] - nm);
            rs += pp;
            const int col = nf * 16 + c;
            *(short*)((char*)&Pl[w][0][0] + prow * 128 +
                      (((col >> 3) ^ (prow & 7)) << 4) + (col & 7) * 2) =
                f2bf_fast(pp);
          }
          lsum[mi][r] += rs;
        }

      // ---- PV: ctx32x128 += P32x64 * V64x128 ----
      bf16x8 ap[2][2];
#pragma unroll
      for (int mi = 0; mi < 2; ++mi)
#pragma unroll
        for (int kc = 0; kc < 2; ++kc) {
          const int prow = mi * 16 + c;
          const int kseg = kc * 4 + g;
          ap[mi][kc] = *(const bf16x8*)((const char*)&Pl[w][0][0] +
                                        prow * 128 +
                                        ((kseg ^ (prow & 7)) << 4));
        }
      __builtin_amdgcn_s_setprio(1);
#pragma unroll
      for (int no = 0; no < 8; ++no) {
#pragma unroll
        for (int kc = 0; kc < 2; ++kc) {
          const int row = no * 16 + c;
          const int seg = kc * 4 + g;
          bf16x8 bv = *(const bf16x8*)((const char*)&Vl[cur][0] + row * 128 +
                                       ((seg ^ (row & 7)) << 4));
#pragma unroll
          for (int mi = 0; mi < 2; ++mi)
            accO[mi][no] = __builtin_amdgcn_mfma_f32_16x16x32_bf16(
                ap[mi][kc], bv, accO[mi][no], 0, 0, 0);
        }
      }
      __builtin_amdgcn_s_setprio(0);
    }

    __syncthreads();
    cur ^= 1;
  }

#pragma unroll
  for (int mi = 0; mi < 2; ++mi) {
    const int qrow = qbase + mi * 16 + g * 4;
#pragma unroll
    for (int r = 0; r < 4; ++r) {
      float ls = lsum[mi][r];  // epilogue cross-lane reduce (once per block)
      ls += __shfl_xor(ls, 1);
      ls += __shfl_xor(ls, 2);
      ls += __shfl_xor(ls, 4);
      ls += __shfl_xor(ls, 8);
      const float inv = 1.f / ls;
#pragma unroll
      for (int no = 0; no < 8; ++no) {
        ctx[((size_t)b * S_LEN + qrow + r) * D_MODEL + h * DK + no * 16 + c] =
            f2bf_fast(accO[mi][no][r] * inv);
      }
    }
  }
}

// -----------------------------------------------------------------------------
extern "C" void kernel_launch(void* const* d_in, const int* in_sizes, int n_in,
                              void* d_out, int out_size, void* d_ws,
                              size_t ws_size, hipStream_t stream) {
  const float* query = (const float*)d_in[0];
  const float* key = (const float*)d_in[1];
  const float* value = (const float*)d_in[2];
  // d_in[3] = mask (known causal tril; not needed)
  const float* W_q = (const float*)d_in[4];
  const float* b_q = (const float*)d_in[5];
  const float* W_k = (const float*)d_in[6];
  const float* b_k = (const float*)d_in[7];
  const float* W_v = (const float*)d_in[8];
  const float* b_v = (const float*)d_in[9];
  const float* W_o = (const float*)d_in[10];
  const float* b_o = (const float*)d_in[11];
  float* out = (float*)d_out;

  char* p = (char*)d_ws;
  const size_t WSZ = (size_t)D_MODEL * D_MODEL * 2;       // 8 MiB
  const size_t XSZ = (size_t)M_TOK * D_MODEL * 2;         // 32 MiB
  short* wq = (short*)p; p += WSZ;
  short* wk = (short*)p; p += WSZ;
  short* wv = (short*)p; p += WSZ;
  short* wo = (short*)p; p += WSZ;
  short* xq = (short*)p; p += XSZ;  // query bf16, later reused as ctx
  short* xk = (short*)p; p += XSZ;  // key bf16
  short* xv = (short*)p; p += XSZ;  // value bf16
  short* Qp = (short*)p; p += XSZ;
  short* Kp = (short*)p; p += XSZ;
  short* Vt = (short*)p; p += XSZ;  // V^T per head

  const int nX8 = (M_TOK * D_MODEL) / 8;
  const int nW8 = (D_MODEL * D_MODEL) / 8;
  cvt3_kernel<<<dim3(1024, 3), 256, 0, stream>>>(query, key, value, xq, xk, xv,
                                                 nX8);
  cvt4_kernel<<<dim3(512, 4), 256, 0, stream>>>(W_q, W_k, W_v, W_o, wq, wk, wv,
                                                wo, nW8);

  const float qscale = 0.12753101829629947f;  // log2(e)/sqrt(128)
  const int ngemm = (M_TOK / 256) * (D_MODEL / 256);  // 256 blocks

  gemm256<0><<<ngemm, 512, 0, stream>>>(xq, wq, b_q, Qp, qscale);
  gemm256<0><<<ngemm, 512, 0, stream>>>(xk, wk, b_k, Kp, 1.0f);
  gemm256<2><<<ngemm, 512, 0, stream>>>(xv, wv, b_v, Vt, 1.0f);

  // 1024 blocks: 64 bh x 16 q-tiles of 128 rows, XCD-mapped in-kernel (LPT)
  attn_kernel<<<dim3(16 * BATCH * NHEADS), 256, 0, stream>>>(Qp, Kp, Vt, xq);

  gemm256<1><<<256, 512, 0, stream>>>(xq, wo, b_o, out, 1.0f);
}

// Round 14
// 491.565 us; speedup vs baseline: 1.1181x; 1.0095x over previous
//
#include <hip/hip_runtime.h>
#include <stdint.h>

#define D_MODEL 2048
#define S_LEN 2048
#define BATCH 4
#define NHEADS 16
#define DK 128
#define M_TOK (BATCH * S_LEN)  // 8192

typedef __attribute__((ext_vector_type(8))) short bf16x8;
typedef __attribute__((ext_vector_type(4))) float f32x4;

__device__ __forceinline__ short f2bf(float f) {  // RNE (GEMM/cvt paths)
  unsigned u = __float_as_uint(f);
  u = (u + 0x7FFF + ((u >> 16) & 1)) >> 16;
  return (short)u;
}
__device__ __forceinline__ short f2bf_fast(float f) {  // round-half-up, 2 ops
  return (short)((__float_as_uint(f) + 0x8000u) >> 16);
}

__device__ __forceinline__ void gl2lds16(const void* g, void* l) {
  __builtin_amdgcn_global_load_lds(
      (const __attribute__((address_space(1))) unsigned int*)g,
      (__attribute__((address_space(3))) unsigned int*)l, 16, 0, 0);
}

#define ASM_BAR() asm volatile("s_barrier" ::: "memory")
#define WAIT_ALL() asm volatile("s_waitcnt vmcnt(0) lgkmcnt(0)" ::: "memory")

// ---------------- fp32 -> bf16 convert (weights only), z-batched -------------
__global__ __launch_bounds__(256) void cvt4_kernel(const float* __restrict__ a0,
                                                   const float* __restrict__ a1,
                                                   const float* __restrict__ a2,
                                                   const float* __restrict__ a3,
                                                   short* o0, short* o1,
                                                   short* o2, short* o3,
                                                   int n8) {
  const float* in = (blockIdx.y == 0)   ? a0
                    : (blockIdx.y == 1) ? a1
                    : (blockIdx.y == 2) ? a2
                                        : a3;
  short* out = (blockIdx.y == 0)   ? o0
               : (blockIdx.y == 1) ? o1
               : (blockIdx.y == 2) ? o2
                                   : o3;
  int i = blockIdx.x * blockDim.x + threadIdx.x;
  const int stride = gridDim.x * blockDim.x;
  for (; i < n8; i += stride) {
    const float4* p = (const float4*)(in + (size_t)i * 8);
    float4 a = p[0], b = p[1];
    bf16x8 o;
    o[0] = f2bf(a.x); o[1] = f2bf(a.y); o[2] = f2bf(a.z); o[3] = f2bf(a.w);
    o[4] = f2bf(b.x); o[5] = f2bf(b.y); o[6] = f2bf(b.z); o[7] = f2bf(b.w);
    *(bf16x8*)(out + (size_t)i * 8) = o;
  }
}

// ---------------- 256x256 GEMM: C[M,N] = A[M,K]*B[N,K]^T + bias --------------
// r7 schedule: ONE waitcnt + ONE s_barrier per K-tile; next tile's staging
// issued as a cluster right after the barrier (loads a full K-tile old).
// AF32=1: A is fp32 in HBM; staged via reg (2x float4 loads at tile-top,
// v_cvt_pk_bf16_f32 + ds_write_b128 after the compute phase = T14 split).
// AF32=0: A staged via global_load_lds (bf16).  B always bf16 gl2lds.
// EPI 0/1: MFMA operands SWAPPED (lane holds 4 consecutive output columns).
// EPI 0: bf16 head-split [B,H,S,DK] scaled by escale. EPI 1: f32 flat [M,N].
// EPI 2: bf16 per-head transposed [B,H,DK,S] (original operand order).
template <int EPI, int AF32>
__global__ __launch_bounds__(512, 2) void gemm256(const void* __restrict__ Ain,
                                                  const short* __restrict__ B,
                                                  const float* __restrict__ bias,
                                                  void* __restrict__ Cout,
                                                  float escale) {
  __shared__ short As[2][256 * 64];
  __shared__ short Bs[2][256 * 64];
  const int t = threadIdx.x, lane = t & 63, w = t >> 6;
  const int c = lane & 15, g = lane >> 4;
  const int wr = w >> 2, wc = w & 3;

  const int cpx = (int)gridDim.x >> 3;
  const int swz = ((int)blockIdx.x & 7) * cpx + ((int)blockIdx.x >> 3);
  const int by = swz >> 3, bx = swz & 7;
  const int row0 = by * 256, col0 = bx * 256;
  const int K = D_MODEL;
  const int NT = K / 64;

  const int srow = t >> 3;
  const int sseg = t & 7;
  const int skk = 8 * (sseg ^ (srow & 7));

  const short* Abase = (const short*)Ain + (size_t)(row0 + srow) * K;
  const float* Afbase = (const float*)Ain + (size_t)(row0 + srow) * K;
  const short* Bbase = B + (size_t)(col0 + srow) * K;

  float4 a4[8];  // AF32 reg-staging: 4 rows x 8 f32

  auto stage_tile = [&](int q, int kt1) {
    if (AF32) {
#pragma unroll
      for (int R = 0; R < 4; ++R) {
        const float4* s =
            (const float4*)(Afbase + (size_t)R * 64 * K + kt1 * 64 + skk);
        a4[R * 2] = s[0];
        a4[R * 2 + 1] = s[1];
      }
    } else {
#pragma unroll
      for (int R = 0; R < 4; ++R)
        gl2lds16(Abase + (size_t)R * 64 * K + kt1 * 64 + skk,
                 &As[q][R * 4096 + t * 8]);
    }
#pragma unroll
    for (int R = 0; R < 4; ++R)
      gl2lds16(Bbase + (size_t)R * 64 * K + kt1 * 64 + skk,
               &Bs[q][R * 4096 + t * 8]);
  };

  auto flushA = [&](int q) {
    if (AF32) {
#pragma unroll
      for (int R = 0; R < 4; ++R) {
        unsigned w0, w1, w2, w3;
        asm("v_cvt_pk_bf16_f32 %0, %1, %2"
            : "=v"(w0)
            : "v"(a4[R * 2].x), "v"(a4[R * 2].y));
        asm("v_cvt_pk_bf16_f32 %0, %1, %2"
            : "=v"(w1)
            : "v"(a4[R * 2].z), "v"(a4[R * 2].w));
        asm("v_cvt_pk_bf16_f32 %0, %1, %2"
            : "=v"(w2)
            : "v"(a4[R * 2 + 1].x), "v"(a4[R * 2 + 1].y));
        asm("v_cvt_pk_bf16_f32 %0, %1, %2"
            : "=v"(w3)
            : "v"(a4[R * 2 + 1].z), "v"(a4[R * 2 + 1].w));
        uint4 pk4;
        pk4.x = w0; pk4.y = w1; pk4.z = w2; pk4.w = w3;
        *(uint4*)&As[q][R * 4096 + t * 8] = pk4;
      }
    }
  };

  f32x4 acc[8][4] = {};

  // prologue: stage K-tile 0 into buf0
  stage_tile(0, 0);
  flushA(0);
  WAIT_ALL();
  ASM_BAR();

  for (int kt = 0; kt < NT; ++kt) {
    const int p = kt & 1, q = p ^ 1;
    const bool more = (kt + 1 < NT);
    if (more) stage_tile(q, kt + 1);  // loads issue now; A-cvt deferred

    const char* abase = (const char*)As[p];
    const char* bbase = (const char*)Bs[p];
#pragma unroll
    for (int ks = 0; ks < 2; ++ks) {
      const int kb = (ks * 64 + g * 16) ^ ((c & 7) << 4);
      bf16x8 bfr[4];
#pragma unroll
      for (int ni = 0; ni < 4; ++ni)
        bfr[ni] = *(const bf16x8*)(bbase + (wc * 64 + ni * 16 + c) * 128 + kb);
#pragma unroll
      for (int mg = 0; mg < 2; ++mg) {
        bf16x8 afr[4];
#pragma unroll
        for (int mi = 0; mi < 4; ++mi)
          afr[mi] = *(const bf16x8*)(abase +
                                     (wr * 128 + mg * 64 + mi * 16 + c) * 128 +
                                     kb);
        __builtin_amdgcn_s_setprio(1);
#pragma unroll
        for (int mi = 0; mi < 4; ++mi)
#pragma unroll
          for (int ni = 0; ni < 4; ++ni) {
            if (EPI == 2)
              acc[mg * 4 + mi][ni] = __builtin_amdgcn_mfma_f32_16x16x32_bf16(
                  afr[mi], bfr[ni], acc[mg * 4 + mi][ni], 0, 0, 0);
            else  // swapped: lane holds 4 consecutive cols (transposed C-frag)
              acc[mg * 4 + mi][ni] = __builtin_amdgcn_mfma_f32_16x16x32_bf16(
                  bfr[ni], afr[mi], acc[mg * 4 + mi][ni], 0, 0, 0);
          }
        __builtin_amdgcn_s_setprio(0);
      }
    }

    if (more) flushA(q);  // cvt+ds_write a full compute-phase after the loads
    WAIT_ALL();           // drain B gl2lds + A ds_writes before publishing
    ASM_BAR();
  }

  if (EPI == 2) {
    // original orientation: lane holds 4 consecutive M-rows (s) at fixed col
#pragma unroll
    for (int ni = 0; ni < 4; ++ni) {
      const int col = col0 + wc * 64 + ni * 16 + c;
      const float bv = bias[col];
#pragma unroll
      for (int m = 0; m < 8; ++m) {
        const int rbase =
            row0 + wr * 128 + (m >> 2) * 64 + (m & 3) * 16 + g * 4;
        const int h = col >> 7, dk = col & 127;
        const int b = rbase >> 11, s0 = rbase & 2047;
        ushort4 pk;
        pk.x = (unsigned short)f2bf(acc[m][ni][0] + bv);
        pk.y = (unsigned short)f2bf(acc[m][ni][1] + bv);
        pk.z = (unsigned short)f2bf(acc[m][ni][2] + bv);
        pk.w = (unsigned short)f2bf(acc[m][ni][3] + bv);
        *(ushort4*)&((short*)Cout)[(((size_t)b * NHEADS + h) * DK + dk) *
                                       S_LEN + s0] = pk;
      }
    }
  } else {
    // swapped orientation: lane holds cols col..col+3 at fixed row s
#pragma unroll
    for (int ni = 0; ni < 4; ++ni) {
      const int col = col0 + wc * 64 + ni * 16 + g * 4;
      const float4 bv4 = *(const float4*)&bias[col];
#pragma unroll
      for (int m = 0; m < 8; ++m) {
        const int s = row0 + wr * 128 + (m >> 2) * 64 + (m & 3) * 16 + c;
        if (EPI == 0) {
          const int h = col >> 7, dk = col & 127;
          const int b = s >> 11, ss = s & 2047;
          ushort4 pk;
          pk.x = (unsigned short)f2bf((acc[m][ni][0] + bv4.x) * escale);
          pk.y = (unsigned short)f2bf((acc[m][ni][1] + bv4.y) * escale);
          pk.z = (unsigned short)f2bf((acc[m][ni][2] + bv4.z) * escale);
          pk.w = (unsigned short)f2bf((acc[m][ni][3] + bv4.w) * escale);
          *(ushort4*)&((short*)Cout)[(((size_t)b * NHEADS + h) * S_LEN + ss) *
                                         DK + dk] = pk;
        } else {
          float4 v;
          v.x = acc[m][ni][0] + bv4.x;
          v.y = acc[m][ni][1] + bv4.y;
          v.z = acc[m][ni][2] + bv4.z;
          v.w = acc[m][ni][3] + bv4.w;
          *(float4*)&((float*)Cout)[(size_t)s * D_MODEL + col] = v;
        }
      }
    }
  }
}

// ---------------- causal flash attention (4 waves, QBLK=128, dbuf, 80KB LDS) -
// Q is PRE-SCALED by log2(e)/sqrt(128) in the Q-GEMM epilogue.
// Block map (r11, proven): bh=((u&7)<<3)|x, qt=15-(u>>3) -> globally
// longest-first dispatch (LPT), uniform work per co-resident cohort.
__global__ __launch_bounds__(256, 2) void attn_kernel(
    const short* __restrict__ Qp, const short* __restrict__ Kp,
    const short* __restrict__ Vt, short* __restrict__ ctx) {
  const int t = threadIdx.x, lane = t & 63, w = t >> 6;  // w in 0..3
  const int c = lane & 15, g = lane >> 4;

  const int fid = blockIdx.x;
  const int x = fid & 7, u = fid >> 3;  // u in 0..127
  const int bh = ((u & 7) << 3) | x;
  const int qt = 15 - (u >> 3);
  const int b = bh >> 4, h = bh & 15;

  __shared__ short Kl[2][64 * 128];  // swizzled: seg ^= row&7   (32 KB)
  __shared__ short Vl[2][128 * 64];  // swizzled: seg ^= row&7   (32 KB)
  __shared__ short Pl[4][32][64];    // swizzled: seg ^= row&7   (16 KB)

  const short* Kbase = Kp + (size_t)bh * S_LEN * DK;
  const short* Vbase = Vt + (size_t)bh * DK * S_LEN;

  const int qbase = qt * 128 + w * 32;
  const short* Qg = Qp + ((size_t)bh * S_LEN + qbase + c) * DK;
  bf16x8 aq[2][4];
#pragma unroll
  for (int mi = 0; mi < 2; ++mi)
#pragma unroll
    for (int kc = 0; kc < 4; ++kc)
      aq[mi][kc] = *(const bf16x8*)(Qg + mi * 16 * DK + kc * 32 + g * 8);

  float mprev[2][4], lsum[2][4];  // lsum = PER-LANE partial (reduced at end)
  f32x4 accO[2][8] = {};
#pragma unroll
  for (int mi = 0; mi < 2; ++mi)
#pragma unroll
    for (int r = 0; r < 4; ++r) {
      mprev[mi][r] = -3.0e38f;
      lsum[mi][r] = 0.f;
    }

  const int nt = 2 * qt + 2;
  const int jmax = (qbase + 31) >> 6;

  auto stage = [&](int buf, int j) {
    const short* Kg = Kbase + (size_t)j * 64 * DK;
#pragma unroll
    for (int ii = 0; ii < 4; ++ii) {
      int s = t + 256 * ii;
      int row = s >> 4, cs = s & 15;
      gl2lds16(Kg + row * DK + (cs ^ (row & 7)) * 8, &Kl[buf][s * 8]);
    }
    const short* Vg = Vbase + j * 64;
#pragma unroll
    for (int ii = 0; ii < 4; ++ii) {
      int s = t + 256 * ii;
      int row = s >> 3, cs = s & 7;
      gl2lds16(Vg + (size_t)row * S_LEN + (cs ^ (row & 7)) * 8,
               &Vl[buf][s * 8]);
    }
  };

  stage(0, 0);
  __syncthreads();
  int cur = 0;

  for (int j = 0; j < nt; ++j) {
    if (j + 1 < nt) stage(cur ^ 1, j + 1);

    if (j <= jmax) {
      // ---- QK^T: 32q x 64k per wave (scores pre-scaled) ----
      f32x4 sa[2][4];
#pragma unroll
      for (int mi = 0; mi < 2; ++mi)
#pragma unroll
        for (int nf = 0; nf < 4; ++nf) sa[mi][nf] = (f32x4){0.f, 0.f, 0.f, 0.f};
      __builtin_amdgcn_s_setprio(1);
#pragma unroll
      for (int nf = 0; nf < 4; ++nf) {
#pragma unroll
        for (int kc = 0; kc < 4; ++kc) {
          const int row = nf * 16 + c;
          const int seg = kc * 4 + g;
          bf16x8 bk = *(const bf16x8*)((const char*)&Kl[cur][0] + row * 256 +
                                       ((seg ^ (row & 7)) << 4));
#pragma unroll
          for (int mi = 0; mi < 2; ++mi)
            sa[mi][nf] = __builtin_amdgcn_mfma_f32_16x16x32_bf16(
                aq[mi][kc], bk, sa[mi][nf], 0, 0, 0);
        }
      }
      __builtin_amdgcn_s_setprio(0);

      // ---- causal mask: wave-uniform branch ----
#pragma unroll
      for (int mi = 0; mi < 2; ++mi) {
        if (j * 64 + 63 > qbase + mi * 16) {
#pragma unroll
          for (int r = 0; r < 4; ++r) {
            const int qglob = qbase + mi * 16 + g * 4 + r;
#pragma unroll
            for (int nf = 0; nf < 4; ++nf)
              if ((j * 64 + nf * 16 + c) > qglob) sa[mi][nf][r] = -3.0e38f;
          }
        }
      }

      // ---- per-lane max + vote (no shuffle tree in the common path) ----
      float lmax[2][4];
      bool need = false;
#pragma unroll
      for (int mi = 0; mi < 2; ++mi)
#pragma unroll
        for (int r = 0; r < 4; ++r) {
          const float m0 = fmaxf(fmaxf(sa[mi][0][r], sa[mi][1][r]),
                                 fmaxf(sa[mi][2][r], sa[mi][3][r]));
          lmax[mi][r] = m0;
          need = need || (m0 > mprev[mi][r] + 5.101f);
        }
      if (__any((int)need)) {  // rare: true row max + rescale
#pragma unroll
        for (int mi = 0; mi < 2; ++mi)
#pragma unroll
          for (int r = 0; r < 4; ++r) {
            float m0 = lmax[mi][r];
            m0 = fmaxf(m0, __shfl_xor(m0, 1));
            m0 = fmaxf(m0, __shfl_xor(m0, 2));
            m0 = fmaxf(m0, __shfl_xor(m0, 4));
            m0 = fmaxf(m0, __shfl_xor(m0, 8));
            const float nm = fmaxf(mprev[mi][r], m0);
            const float corr = exp2f(mprev[mi][r] - nm);
            lsum[mi][r] *= corr;
#pragma unroll
            for (int no = 0; no < 8; ++no) accO[mi][no][r] *= corr;
            mprev[mi][r] = nm;
          }
      }

      // ---- exp2 + P store (cheap round) + per-lane lsum partial ----
#pragma unroll
      for (int mi = 0; mi < 2; ++mi)
#pragma unroll
        for (int r = 0; r < 4; ++r) {
          const float nm = mprev[mi][r];
          const int prow = mi * 16 + g * 4 + r;
          float rs = 0.f;
#pragma unroll
          for (int nf = 0; nf < 4; ++nf) {
            const float pp = exp2f(sa[mi][nf][r] - nm);
            rs += pp;
            const int col = nf * 16 + c;
            *(short*)((char*)&Pl[w][0][0] + prow * 128 +
                      (((col >> 3) ^ (prow & 7)) << 4) + (col & 7) * 2) =
                f2bf_fast(pp);
          }
          lsum[mi][r] += rs;
        }

      // ---- PV: ctx32x128 += P32x64 * V64x128 ----
      bf16x8 ap[2][2];
#pragma unroll
      for (int mi = 0; mi < 2; ++mi)
#pragma unroll
        for (int kc = 0; kc < 2; ++kc) {
          const int prow = mi * 16 + c;
          const int kseg = kc * 4 + g;
          ap[mi][kc] = *(const bf16x8*)((const char*)&Pl[w][0][0] +
                                        prow * 128 +
                                        ((kseg ^ (prow & 7)) << 4));
        }
      __builtin_amdgcn_s_setprio(1);
#pragma unroll
      for (int no = 0; no < 8; ++no) {
#pragma unroll
        for (int kc = 0; kc < 2; ++kc) {
          const int row = no * 16 + c;
          const int seg = kc * 4 + g;
          bf16x8 bv = *(const bf16x8*)((const char*)&Vl[cur][0] + row * 128 +
                                       ((seg ^ (row & 7)) << 4));
#pragma unroll
          for (int mi = 0; mi < 2; ++mi)
            accO[mi][no] = __builtin_amdgcn_mfma_f32_16x16x32_bf16(
                ap[mi][kc], bv, accO[mi][no], 0, 0, 0);
        }
      }
      __builtin_amdgcn_s_setprio(0);
    }

    __syncthreads();
    cur ^= 1;
  }

#pragma unroll
  for (int mi = 0; mi < 2; ++mi) {
    const int qrow = qbase + mi * 16 + g * 4;
#pragma unroll
    for (int r = 0; r < 4; ++r) {
      float ls = lsum[mi][r];  // epilogue cross-lane reduce (once per block)
      ls += __shfl_xor(ls, 1);
      ls += __shfl_xor(ls, 2);
      ls += __shfl_xor(ls, 4);
      ls += __shfl_xor(ls, 8);
      const float inv = 1.f / ls;
#pragma unroll
      for (int no = 0; no < 8; ++no) {
        ctx[((size_t)b * S_LEN + qrow + r) * D_MODEL + h * DK + no * 16 + c] =
            f2bf_fast(accO[mi][no][r] * inv);
      }
    }
  }
}

// -----------------------------------------------------------------------------
extern "C" void kernel_launch(void* const* d_in, const int* in_sizes, int n_in,
                              void* d_out, int out_size, void* d_ws,
                              size_t ws_size, hipStream_t stream) {
  const float* query = (const float*)d_in[0];
  const float* key = (const float*)d_in[1];
  const float* value = (const float*)d_in[2];
  // d_in[3] = mask (known causal tril; not needed)
  const float* W_q = (const float*)d_in[4];
  const float* b_q = (const float*)d_in[5];
  const float* W_k = (const float*)d_in[6];
  const float* b_k = (const float*)d_in[7];
  const float* W_v = (const float*)d_in[8];
  const float* b_v = (const float*)d_in[9];
  const float* W_o = (const float*)d_in[10];
  const float* b_o = (const float*)d_in[11];
  float* out = (float*)d_out;

  char* p = (char*)d_ws;
  const size_t WSZ = (size_t)D_MODEL * D_MODEL * 2;       // 8 MiB
  const size_t XSZ = (size_t)M_TOK * D_MODEL * 2;         // 32 MiB
  short* wq = (short*)p; p += WSZ;
  short* wk = (short*)p; p += WSZ;
  short* wv = (short*)p; p += WSZ;
  short* wo = (short*)p; p += WSZ;
  short* ctxb = (short*)p; p += XSZ;  // attn output (bf16)
  short* Qp = (short*)p; p += XSZ;
  short* Kp = (short*)p; p += XSZ;
  short* Vt = (short*)p; p += XSZ;    // V^T per head

  const int nW8 = (D_MODEL * D_MODEL) / 8;
  cvt4_kernel<<<dim3(512, 4), 256, 0, stream>>>(W_q, W_k, W_v, W_o, wq, wk, wv,
                                                wo, nW8);

  const float qscale = 0.12753101829629947f;  // log2(e)/sqrt(128)
  const int ngemm = (M_TOK / 256) * (D_MODEL / 256);  // 256 blocks

  // QKV GEMMs read fp32 activations directly (fused convert in A-staging).
  gemm256<0, 1><<<ngemm, 512, 0, stream>>>(query, wq, b_q, Qp, qscale);
  gemm256<0, 1><<<ngemm, 512, 0, stream>>>(key, wk, b_k, Kp, 1.0f);
  gemm256<2, 1><<<ngemm, 512, 0, stream>>>(value, wv, b_v, Vt, 1.0f);

  // 1024 blocks: 64 bh x 16 q-tiles of 128 rows, XCD-mapped in-kernel (LPT)
  attn_kernel<<<dim3(16 * BATCH * NHEADS), 256, 0, stream>>>(Qp, Kp, Vt, ctxb);

  gemm256<1, 0><<<256, 512, 0, stream>>>(ctxb, wo, b_o, out, 1.0f);
}